// Round 4
// baseline (504.514 us; speedup 1.0000x reference)
//
#include <hip/hip_runtime.h>

#define S 48
#define T 16
#define NTOT (2 * S * S * S * T) // 3,538,944

// P-type (B,S,S,S,T) element strides: z:16 x:768 y:36864 b:1769472
// V/F  (B,S,S,S,3,T) element strides: ch:16 z:48 x:2304 y:110592 b:5308416

__device__ __forceinline__ float4 ld4(const float* p) {
    return *reinterpret_cast<const float4*>(p);
}
__device__ __forceinline__ float4 operator-(float4 a, float4 b) {
    return make_float4(a.x - b.x, a.y - b.y, a.z - b.z, a.w - b.w);
}
__device__ __forceinline__ float4 operator+(float4 a, float4 b) {
    return make_float4(a.x + b.x, a.y + b.y, a.z + b.z, a.w + b.w);
}
__device__ __forceinline__ float4 operator*(float s, float4 a) {
    return make_float4(s * a.x, s * a.y, s * a.z, s * a.w);
}
__device__ __forceinline__ float4 operator*(float4 a, float4 b) {
    return make_float4(a.x * b.x, a.y * b.y, a.z * b.z, a.w * b.w);
}
__device__ __forceinline__ float sum2(float4 a) {
    return a.x * a.x + a.y * a.y + a.z * a.z + a.w * a.w;
}

// Per-axis stencil parameters (branchless; coefficients zero out clamped taps).
// g1 = w*(p1 - m1)
// g2 (composed grad-of-grad) = cm2*m2 + cm1*m1 + cc*c + cp1*p1 + cp2*p2
struct AxisP {
    int om2, om1, op1, op2; // tap offsets in stride units, clamped into range
    float w, cm2, cm1, cc, cp1, cp2;
};
__device__ __forceinline__ AxisP axis_params(int i, int N) {
    AxisP a;
    a.om1 = (i > 0) ? -1 : 0;
    a.op1 = (i < N - 1) ? 1 : 0;
    a.om2 = (i >= 2) ? -2 : 0;
    a.op2 = (i < N - 2) ? 2 : 0;
    a.w   = (i > 0 && i < N - 1) ? 0.5f : 1.0f;
    a.cm2 = (i < 2) ? 0.0f : ((i == N - 1) ? 0.5f : 0.25f);
    a.cm1 = (i == 1) ? 0.5f : ((i == N - 1) ? -1.0f : 0.0f);
    a.cc  = (i == 0) ? 0.5f : (i == 1 || i == N - 2) ? -0.75f : (i == N - 1) ? 0.5f : -0.5f;
    a.cp1 = (i == 0) ? -1.0f : ((i == N - 2) ? 0.5f : 0.0f);
    a.cp2 = (i == 0) ? 0.5f : (i == 1) ? 0.25f : (i < N - 2) ? 0.25f : 0.0f;
    return a;
}

// first + composed-second derivative along one axis; c = already-loaded center
__device__ __forceinline__ void gboth(const float* __restrict__ fc, float4 c,
                                      const AxisP& a, int stride,
                                      float4& g1, float4& g2) {
    const float4 m2 = ld4(fc + a.om2 * stride);
    const float4 m1 = ld4(fc + a.om1 * stride);
    const float4 p1 = ld4(fc + a.op1 * stride);
    const float4 p2 = ld4(fc + a.op2 * stride);
    g1 = a.w * (p1 - m1);
    g2 = a.cm2 * m2 + a.cm1 * m1 + a.cc * c + a.cp1 * p1 + a.cp2 * p2;
}

// d/dt for elements t0..t0+3 (row length 16, t0 in {0,4,8,12}); c = center vector
__device__ __forceinline__ float4 d1t(float4 c, const float* __restrict__ fc, int t0) {
    float4 r;
    r.x = (t0 == 0) ? (c.y - c.x) : (c.y - fc[-1]) * 0.5f;
    r.y = (c.z - c.x) * 0.5f;
    r.z = (c.w - c.y) * 0.5f;
    r.w = (t0 == 12) ? (c.w - c.z) : (fc[4] - c.z) * 0.5f;
    return r;
}

// grid (48,48,2) = (x, y, b); block 192 = 48 z * 4 t-chunks
__global__ __launch_bounds__(192, 4) void fused_loss(
    const float* __restrict__ Cmat, const float* __restrict__ V,
    const float* __restrict__ P, const float* __restrict__ Xa,
    const float* __restrict__ X1a, const float* __restrict__ F,
    const float* __restrict__ Rep, const float* __restrict__ Xlast,
    const float* __restrict__ Y, float* __restrict__ ws)
{
    const int x = blockIdx.x, y = blockIdx.y, b = blockIdx.z;
    const int tid = threadIdx.x;
    const int z  = tid >> 2;
    const int t0 = (tid & 3) << 2;

    const float re = Rep[0];

    // wave-uniform stencil params (x, y) -> SGPRs; per-lane only for z
    const AxisP az = axis_params(z, S);
    const AxisP ax = axis_params(x, S);
    const AxisP ay = axis_params(y, S);

    // block-uniform bases
    const int base_p = b * 1769472 + y * 36864 + x * 768;  // + z*16 + t0 = +4*tid
    const int base_v = b * 5308416 + y * 110592 + x * 2304; // + z*48 + t0
    const int sp     = ((b * S + y) * S + x) * S + z;

    float am1, am2, aphy = 0.f, at1, at2;
    {
        const int prow = base_p + 4 * tid;

        // ---- elementwise losses ----
        const float4 yv  = ld4(Y + prow);
        const float4 x1v = ld4(X1a + prow);
        const float4 xv  = ld4(Xa + prow);
        const float4 cvv = ld4(Cmat + prow);
        am1 = sum2(x1v - yv);
        am2 = sum2(xv - yv);
        at2 = sum2(cvv - yv);
        const float yp0 = (t0 == 0) ? Xlast[sp] : Y[prow - 1];
        at1 = sum2(make_float4(yp0, yv.x, yv.y, yv.z) - yv);

        // ---- P first derivatives (no center needed) ----
        const float* Pc = P + prow;
        const float4 dPdz = az.w * (ld4(Pc + az.op1 * 16)    - ld4(Pc + az.om1 * 16));
        const float4 dPdx = ax.w * (ld4(Pc + ax.op1 * 768)   - ld4(Pc + ax.om1 * 768));
        const float4 dPdy = ay.w * (ld4(Pc + ay.op1 * 36864) - ld4(Pc + ay.om1 * 36864));

        // ---- velocity centers (channels at +0,+16,+32) ----
        const float* Vyc = V + base_v + z * 48 + t0;
        const float* Vxc = Vyc + 16;
        const float* Vzc = Vyc + 32;
        const float4 vy = ld4(Vyc), vx = ld4(Vxc), vz = ld4(Vzc);

        float4 e4 = make_float4(0.f, 0.f, 0.f, 0.f);

        // ---- channel 0: Vy ----
        {
            float4 dz, lz, dx_, lx, dy_, ly;
            gboth(Vyc, vy, az, 48, dz, lz);
            gboth(Vyc, vy, ax, 2304, dx_, lx);
            gboth(Vyc, vy, ay, 110592, dy_, ly);
            const float4 dt = d1t(vy, Vyc, t0);
            const float4 fy = ld4(F + base_v + z * 48 + t0);
            const float4 e = dt + vx * dx_ + vy * dy_ + vz * dz + dPdy
                             + (-re) * (lz + lx + ly) + fy;
            aphy += sum2(e);
            e4 = e4 + dy_;
        }
        // ---- channel 1: Vx ----
        {
            float4 dz, lz, dx_, lx, dy_, ly;
            gboth(Vxc, vx, az, 48, dz, lz);
            gboth(Vxc, vx, ax, 2304, dx_, lx);
            gboth(Vxc, vx, ay, 110592, dy_, ly);
            const float4 dt = d1t(vx, Vxc, t0);
            const float4 fx = ld4(F + base_v + z * 48 + t0 + 16);
            const float4 e = dt + vx * dx_ + vy * dy_ + vz * dz + dPdx
                             + (-re) * (lz + lx + ly) + fx;
            aphy += sum2(e);
            e4 = e4 + dx_;
        }
        // ---- channel 2: Vz ----
        {
            float4 dz, lz, dx_, lx, dy_, ly;
            gboth(Vzc, vz, az, 48, dz, lz);
            gboth(Vzc, vz, ax, 2304, dx_, lx);
            gboth(Vzc, vz, ay, 110592, dy_, ly);
            const float4 dt = d1t(vz, Vzc, t0);
            const float4 fz = ld4(F + base_v + z * 48 + t0 + 32);
            const float4 e = dt + vx * dx_ + vy * dy_ + vz * dz + dPdz
                             + (-re) * (lz + lx + ly) + fz;
            aphy += sum2(e);
            e4 = e4 + dz;
        }
        aphy += sum2(e4);
    }

    // ---- reduction: wave shuffle -> LDS -> 5 atomics per block ----
    #pragma unroll
    for (int off = 32; off > 0; off >>= 1) {
        am1  += __shfl_down(am1, off);
        am2  += __shfl_down(am2, off);
        aphy += __shfl_down(aphy, off);
        at1  += __shfl_down(at1, off);
        at2  += __shfl_down(at2, off);
    }
    __shared__ float sred[3][5];
    const int lane = tid & 63;
    const int wv   = tid >> 6;
    if (lane == 0) {
        sred[wv][0] = am1; sred[wv][1] = am2; sred[wv][2] = aphy;
        sred[wv][3] = at1; sred[wv][4] = at2;
    }
    __syncthreads();
    if (tid == 0) {
        float s0 = 0.f, s1 = 0.f, s2 = 0.f, s3 = 0.f, s4 = 0.f;
        #pragma unroll
        for (int w = 0; w < 3; ++w) {
            s0 += sred[w][0]; s1 += sred[w][1]; s2 += sred[w][2];
            s3 += sred[w][3]; s4 += sred[w][4];
        }
        atomicAdd(&ws[0], s0);
        atomicAdd(&ws[1], s1);
        atomicAdd(&ws[2], s2);
        atomicAdd(&ws[3], s3);
        atomicAdd(&ws[4], s4);
    }
}

__global__ void finalize_kernel(const float* __restrict__ ws, float* __restrict__ out) {
    const float invN = 1.0f / (float)NTOT;
    const float m1  = ws[0] * invN;
    const float m2  = ws[1] * invN;
    const float phy = ws[2] * invN;
    const float t1  = ws[3] * invN;
    const float t2  = ws[4] * invN;
    out[0] = m1;
    out[1] = m2;
    out[2] = phy;
    out[3] = (t1 < t2) ? (t2 - t1) : 0.0f;
}

extern "C" void kernel_launch(void* const* d_in, const int* in_sizes, int n_in,
                              void* d_out, int out_size, void* d_ws, size_t ws_size,
                              hipStream_t stream) {
    // 0 C_all, 1 V_all, 2 P_all, 3 X_all, 4 X1_all, 5 F_all, 6 Re, 7 X_last,
    // 8 Y_data, 9 maskd0, 10 maskd1, 11 maskd2
    const float* Cmat  = (const float*)d_in[0];
    const float* V     = (const float*)d_in[1];
    const float* P     = (const float*)d_in[2];
    const float* Xa    = (const float*)d_in[3];
    const float* X1a   = (const float*)d_in[4];
    const float* F     = (const float*)d_in[5];
    const float* Rep   = (const float*)d_in[6];
    const float* Xlast = (const float*)d_in[7];
    const float* Y     = (const float*)d_in[8];

    float* ws  = (float*)d_ws;
    float* out = (float*)d_out;

    hipMemsetAsync(ws, 0, 5 * sizeof(float), stream);
    dim3 grid(S, S, 2);
    fused_loss<<<grid, 192, 0, stream>>>(Cmat, V, P, Xa, X1a, F, Rep, Xlast, Y, ws);
    finalize_kernel<<<1, 1, 0, stream>>>(ws, out);
}

// Round 5
// 443.965 us; speedup vs baseline: 1.1364x; 1.1364x over previous
//
#include <hip/hip_runtime.h>

#define S 48
#define T 16
#define NTOT (2 * S * S * S * T) // 3,538,944

// P-type (B,S,S,S,T) element strides: z:16 x:768 y:36864 b:1769472
// V/F  (B,S,S,S,3,T) element strides: ch:16 z:48 x:2304 y:110592 b:5308416

__device__ __forceinline__ float4 ld4(const float* p) {
    return *reinterpret_cast<const float4*>(p);
}
__device__ __forceinline__ float4 lds4(const float* p) {
    return *reinterpret_cast<const float4*>(p);
}
__device__ __forceinline__ float4 operator-(float4 a, float4 b) {
    return make_float4(a.x - b.x, a.y - b.y, a.z - b.z, a.w - b.w);
}
__device__ __forceinline__ float4 operator+(float4 a, float4 b) {
    return make_float4(a.x + b.x, a.y + b.y, a.z + b.z, a.w + b.w);
}
__device__ __forceinline__ float4 operator*(float s, float4 a) {
    return make_float4(s * a.x, s * a.y, s * a.z, s * a.w);
}
__device__ __forceinline__ float4 operator*(float4 a, float4 b) {
    return make_float4(a.x * b.x, a.y * b.y, a.z * b.z, a.w * b.w);
}
__device__ __forceinline__ float sum2(float4 a) {
    return a.x * a.x + a.y * a.y + a.z * a.z + a.w * a.w;
}

// Per-axis stencil params (branchless; coefficients zero out clamped taps).
// g1 = w*(p1 - m1)
// g2 (composed grad-of-grad) = cm2*m2 + cm1*m1 + cc*c + cp1*p1 + cp2*p2
struct AxisP {
    int om2, om1, op1, op2; // tap offsets in stride units, clamped into range
    float w, cm2, cm1, cc, cp1, cp2;
};
__device__ __forceinline__ AxisP axis_params(int i, int N) {
    AxisP a;
    a.om1 = (i > 0) ? -1 : 0;
    a.op1 = (i < N - 1) ? 1 : 0;
    a.om2 = (i >= 2) ? -2 : 0;
    a.op2 = (i < N - 2) ? 2 : 0;
    a.w   = (i > 0 && i < N - 1) ? 0.5f : 1.0f;
    a.cm2 = (i < 2) ? 0.0f : ((i == N - 1) ? 0.5f : 0.25f);
    a.cm1 = (i == 1) ? 0.5f : ((i == N - 1) ? -1.0f : 0.0f);
    a.cc  = (i == 0) ? 0.5f : (i == 1 || i == N - 2) ? -0.75f : (i == N - 1) ? 0.5f : -0.5f;
    a.cp1 = (i == 0) ? -1.0f : ((i == N - 2) ? 0.5f : 0.0f);
    a.cp2 = (i == 0) ? 0.5f : (i == 1) ? 0.25f : (i < N - 2) ? 0.25f : 0.0f;
    return a;
}

// global first + composed-second derivative along one axis; c = center (in regs)
__device__ __forceinline__ void gboth_g(const float* __restrict__ fc, float4 c,
                                        const AxisP& a, int stride,
                                        float4& g1, float4& g2) {
    const float4 m2 = ld4(fc + a.om2 * stride);
    const float4 m1 = ld4(fc + a.om1 * stride);
    const float4 p1 = ld4(fc + a.op1 * stride);
    const float4 p2 = ld4(fc + a.op2 * stride);
    g1 = a.w * (p1 - m1);
    g2 = a.cm2 * m2 + a.cm1 * m1 + a.cc * c + a.cp1 * p1 + a.cp2 * p2;
}

// same but taps from LDS (z axis, stride 16 floats)
__device__ __forceinline__ void gboth_l(const float* sbuf, int f, float4 c,
                                        const AxisP& a, float4& g1, float4& g2) {
    const float4 m2 = lds4(sbuf + f + a.om2 * 16);
    const float4 m1 = lds4(sbuf + f + a.om1 * 16);
    const float4 p1 = lds4(sbuf + f + a.op1 * 16);
    const float4 p2 = lds4(sbuf + f + a.op2 * 16);
    g1 = a.w * (p1 - m1);
    g2 = a.cm2 * m2 + a.cm1 * m1 + a.cc * c + a.cp1 * p1 + a.cp2 * p2;
}

// d/dt for elements t0..t0+3 (T=16, t0 in {0,4,8,12}); c = center; sbuf+f = center in LDS
__device__ __forceinline__ float4 d1t_l(float4 c, const float* sbuf, int f, int t0) {
    float4 r;
    r.x = (t0 == 0) ? (c.y - c.x) : (c.y - sbuf[f - 1]) * 0.5f;
    r.y = (c.z - c.x) * 0.5f;
    r.z = (c.w - c.y) * 0.5f;
    r.w = (t0 == 12) ? (c.w - c.z) : (sbuf[f + 4] - c.z) * 0.5f;
    return r;
}

// grid (48,48,2) = (x, y, b); block 192 = 48 z * 4 t-chunks
__global__ __launch_bounds__(192) void fused_loss(
    const float* __restrict__ Cmat, const float* __restrict__ V,
    const float* __restrict__ P, const float* __restrict__ Xa,
    const float* __restrict__ X1a, const float* __restrict__ F,
    const float* __restrict__ Rep, const float* __restrict__ Xlast,
    const float* __restrict__ Y, float* __restrict__ ws)
{
    __shared__ float sVy[768], sVx[768], sVz[768], sP[768], sY[768];

    const int x = blockIdx.x, y = blockIdx.y, b = blockIdx.z;
    const int tid = threadIdx.x;
    const int z  = tid >> 2;
    const int t0 = (tid & 3) << 2;
    const int f  = tid << 2;          // flat float index in LDS column

    const float re = Rep[0];

    const AxisP az = axis_params(z, S);  // per-lane (z)
    const AxisP ax = axis_params(x, S);  // wave-uniform
    const AxisP ay = axis_params(y, S);  // wave-uniform

    const int base_p = b * 1769472 + y * 36864 + x * 768;   // + f
    const int base_v = b * 5308416 + y * 110592 + x * 2304; // + z*48 + t0
    const int sp     = ((b * S + y) * S + x) * S + z;
    const int prow   = base_p + f;
    const int vrow   = base_v + z * 48 + t0;

    // ---- stage center column into LDS ----
    const float4 yv = ld4(Y + prow);
    const float4 pc = ld4(P + prow);
    const float4 vy = ld4(V + vrow);
    const float4 vx = ld4(V + vrow + 16);
    const float4 vz = ld4(V + vrow + 32);
    *reinterpret_cast<float4*>(&sY[f])  = yv;
    *reinterpret_cast<float4*>(&sP[f])  = pc;
    *reinterpret_cast<float4*>(&sVy[f]) = vy;
    *reinterpret_cast<float4*>(&sVx[f]) = vx;
    *reinterpret_cast<float4*>(&sVz[f]) = vz;
    __syncthreads();

    float am1, am2, aphy = 0.f, at1, at2;
    {
        // ---- elementwise losses ----
        const float4 x1v = ld4(X1a + prow);
        const float4 xv  = ld4(Xa + prow);
        const float4 cvv = ld4(Cmat + prow);
        am1 = sum2(x1v - yv);
        am2 = sum2(xv - yv);
        at2 = sum2(cvv - yv);
        const float yp0 = (t0 == 0) ? Xlast[sp] : sY[f - 1];
        at1 = sum2(make_float4(yp0, yv.x, yv.y, yv.z) - yv);

        // ---- P first derivatives: z from LDS, x/y from global ----
        const float4 dPdz = az.w * (lds4(sP + f + az.op1 * 16) - lds4(sP + f + az.om1 * 16));
        const float* Pc = P + prow;
        const float4 dPdx = ax.w * (ld4(Pc + ax.op1 * 768)   - ld4(Pc + ax.om1 * 768));
        const float4 dPdy = ay.w * (ld4(Pc + ay.op1 * 36864) - ld4(Pc + ay.om1 * 36864));

        const float* Vyc = V + vrow;
        const float* Vxc = Vyc + 16;
        const float* Vzc = Vyc + 32;

        float4 e4 = make_float4(0.f, 0.f, 0.f, 0.f);

        // ---- channel 0: Vy ----
        {
            float4 dz, lz, dx_, lx, dy_, ly;
            gboth_l(sVy, f, vy, az, dz, lz);
            gboth_g(Vyc, vy, ax, 2304, dx_, lx);
            gboth_g(Vyc, vy, ay, 110592, dy_, ly);
            const float4 dt = d1t_l(vy, sVy, f, t0);
            const float4 fy = ld4(F + vrow);
            const float4 e = dt + vx * dx_ + vy * dy_ + vz * dz + dPdy
                             + (-re) * (lz + lx + ly) + fy;
            aphy += sum2(e);
            e4 = e4 + dy_;
        }
        // ---- channel 1: Vx ----
        {
            float4 dz, lz, dx_, lx, dy_, ly;
            gboth_l(sVx, f, vx, az, dz, lz);
            gboth_g(Vxc, vx, ax, 2304, dx_, lx);
            gboth_g(Vxc, vx, ay, 110592, dy_, ly);
            const float4 dt = d1t_l(vx, sVx, f, t0);
            const float4 fx = ld4(F + vrow + 16);
            const float4 e = dt + vx * dx_ + vy * dy_ + vz * dz + dPdx
                             + (-re) * (lz + lx + ly) + fx;
            aphy += sum2(e);
            e4 = e4 + dx_;
        }
        // ---- channel 2: Vz ----
        {
            float4 dz, lz, dx_, lx, dy_, ly;
            gboth_l(sVz, f, vz, az, dz, lz);
            gboth_g(Vzc, vz, ax, 2304, dx_, lx);
            gboth_g(Vzc, vz, ay, 110592, dy_, ly);
            const float4 dt = d1t_l(vz, sVz, f, t0);
            const float4 fz = ld4(F + vrow + 32);
            const float4 e = dt + vx * dx_ + vy * dy_ + vz * dz + dPdz
                             + (-re) * (lz + lx + ly) + fz;
            aphy += sum2(e);
            e4 = e4 + dz;
        }
        aphy += sum2(e4);
    }

    // ---- reduction: wave shuffle -> LDS -> 5 atomics per block ----
    #pragma unroll
    for (int off = 32; off > 0; off >>= 1) {
        am1  += __shfl_down(am1, off);
        am2  += __shfl_down(am2, off);
        aphy += __shfl_down(aphy, off);
        at1  += __shfl_down(at1, off);
        at2  += __shfl_down(at2, off);
    }
    __shared__ float sred[3][5];
    const int lane = tid & 63;
    const int wv   = tid >> 6;
    if (lane == 0) {
        sred[wv][0] = am1; sred[wv][1] = am2; sred[wv][2] = aphy;
        sred[wv][3] = at1; sred[wv][4] = at2;
    }
    __syncthreads();
    if (tid == 0) {
        float s0 = 0.f, s1 = 0.f, s2 = 0.f, s3 = 0.f, s4 = 0.f;
        #pragma unroll
        for (int w = 0; w < 3; ++w) {
            s0 += sred[w][0]; s1 += sred[w][1]; s2 += sred[w][2];
            s3 += sred[w][3]; s4 += sred[w][4];
        }
        atomicAdd(&ws[0], s0);
        atomicAdd(&ws[1], s1);
        atomicAdd(&ws[2], s2);
        atomicAdd(&ws[3], s3);
        atomicAdd(&ws[4], s4);
    }
}

__global__ void finalize_kernel(const float* __restrict__ ws, float* __restrict__ out) {
    const float invN = 1.0f / (float)NTOT;
    const float m1  = ws[0] * invN;
    const float m2  = ws[1] * invN;
    const float phy = ws[2] * invN;
    const float t1  = ws[3] * invN;
    const float t2  = ws[4] * invN;
    out[0] = m1;
    out[1] = m2;
    out[2] = phy;
    out[3] = (t1 < t2) ? (t2 - t1) : 0.0f;
}

extern "C" void kernel_launch(void* const* d_in, const int* in_sizes, int n_in,
                              void* d_out, int out_size, void* d_ws, size_t ws_size,
                              hipStream_t stream) {
    // 0 C_all, 1 V_all, 2 P_all, 3 X_all, 4 X1_all, 5 F_all, 6 Re, 7 X_last,
    // 8 Y_data, 9 maskd0, 10 maskd1, 11 maskd2
    const float* Cmat  = (const float*)d_in[0];
    const float* V     = (const float*)d_in[1];
    const float* P     = (const float*)d_in[2];
    const float* Xa    = (const float*)d_in[3];
    const float* X1a   = (const float*)d_in[4];
    const float* F     = (const float*)d_in[5];
    const float* Rep   = (const float*)d_in[6];
    const float* Xlast = (const float*)d_in[7];
    const float* Y     = (const float*)d_in[8];

    float* ws  = (float*)d_ws;
    float* out = (float*)d_out;

    hipMemsetAsync(ws, 0, 5 * sizeof(float), stream);
    dim3 grid(S, S, 2);
    fused_loss<<<grid, 192, 0, stream>>>(Cmat, V, P, Xa, X1a, F, Rep, Xlast, Y, ws);
    finalize_kernel<<<1, 1, 0, stream>>>(ws, out);
}

// Round 6
// 335.011 us; speedup vs baseline: 1.5060x; 1.3252x over previous
//
#include <hip/hip_runtime.h>

#define S 48
#define T 16
#define NTOT (2 * S * S * S * T) // 3,538,944
#define NC (NTOT / 4)            // 884,736 float4-chunks

// P-type (B,S,S,S,T) element strides: z:16 x:768 y:36864 b:1769472
// V/F  (B,S,S,S,3,T) element strides: ch:16 z:48 x:2304 y:110592 b:5308416

__device__ __forceinline__ float4 ld4(const float* p) {
    return *reinterpret_cast<const float4*>(p);
}
__device__ __forceinline__ float4 operator-(float4 a, float4 b) {
    return make_float4(a.x - b.x, a.y - b.y, a.z - b.z, a.w - b.w);
}
__device__ __forceinline__ float4 operator+(float4 a, float4 b) {
    return make_float4(a.x + b.x, a.y + b.y, a.z + b.z, a.w + b.w);
}
__device__ __forceinline__ float4 operator*(float s, float4 a) {
    return make_float4(s * a.x, s * a.y, s * a.z, s * a.w);
}
__device__ __forceinline__ float4 operator*(float4 a, float4 b) {
    return make_float4(a.x * b.x, a.y * b.y, a.z * b.z, a.w * b.w);
}
__device__ __forceinline__ float sum2(float4 a) {
    return a.x * a.x + a.y * a.y + a.z * a.z + a.w * a.w;
}

// Per-axis stencil params (branchless; coefficients zero out clamped taps).
// g1 = w*(p1 - m1)
// g2 (composed grad-of-grad) = cm2*m2 + cm1*m1 + cc*c + cp1*p1 + cp2*p2
struct AxisP {
    int om2, om1, op1, op2;
    float w, cm2, cm1, cc, cp1, cp2;
};
__device__ __forceinline__ AxisP axis_params(int i, int N) {
    AxisP a;
    a.om1 = (i > 0) ? -1 : 0;
    a.op1 = (i < N - 1) ? 1 : 0;
    a.om2 = (i >= 2) ? -2 : 0;
    a.op2 = (i < N - 2) ? 2 : 0;
    a.w   = (i > 0 && i < N - 1) ? 0.5f : 1.0f;
    a.cm2 = (i < 2) ? 0.0f : ((i == N - 1) ? 0.5f : 0.25f);
    a.cm1 = (i == 1) ? 0.5f : ((i == N - 1) ? -1.0f : 0.0f);
    a.cc  = (i == 0) ? 0.5f : (i == 1 || i == N - 2) ? -0.75f : (i == N - 1) ? 0.5f : -0.5f;
    a.cp1 = (i == 0) ? -1.0f : ((i == N - 2) ? 0.5f : 0.0f);
    a.cp2 = (i == 0) ? 0.5f : (i == 1) ? 0.25f : (i < N - 2) ? 0.25f : 0.0f;
    return a;
}

// first + composed-second derivative along one axis; c = already-loaded center
__device__ __forceinline__ void gboth_g(const float* __restrict__ fc, float4 c,
                                        const AxisP& a, int stride,
                                        float4& g1, float4& g2) {
    const float4 m2 = ld4(fc + a.om2 * stride);
    const float4 m1 = ld4(fc + a.om1 * stride);
    const float4 p1 = ld4(fc + a.op1 * stride);
    const float4 p2 = ld4(fc + a.op2 * stride);
    g1 = a.w * (p1 - m1);
    g2 = a.cm2 * m2 + a.cm1 * m1 + a.cc * c + a.cp1 * p1 + a.cp2 * p2;
}

// d/dt for elements t0..t0+3 (T=16, t0 in {0,4,8,12}); c = center vector
__device__ __forceinline__ float4 d1t(float4 c, const float* __restrict__ fc, int t0) {
    float4 r;
    r.x = (t0 == 0) ? (c.y - c.x) : (c.y - fc[-1]) * 0.5f;
    r.y = (c.z - c.x) * 0.5f;
    r.z = (c.w - c.y) * 0.5f;
    r.w = (t0 == 12) ? (c.w - c.z) : (fc[4] - c.z) * 0.5f;
    return r;
}

// ---------------- physics kernel ----------------
// grid (48 x, 12 y-groups, 2 b); block 192 = 48 z * 4 t-chunks; loop 4 y each.
__global__ __launch_bounds__(192) void phys_loss(
    const float* __restrict__ V, const float* __restrict__ P,
    const float* __restrict__ F, const float* __restrict__ Rep,
    float* __restrict__ ws)
{
    const int x = blockIdx.x, yg = blockIdx.y, b = blockIdx.z;
    const int tid = threadIdx.x;
    const int z  = tid >> 2;
    const int t0 = (tid & 3) << 2;

    const float re = Rep[0];
    const AxisP az = axis_params(z, S); // per-lane
    const AxisP ax = axis_params(x, S); // block-uniform -> SGPR

    int y = yg << 2;
    const float* Pc  = P + b * 1769472 + y * 36864 + x * 768 + (tid << 2);
    const float* Vyc = V + b * 5308416 + y * 110592 + x * 2304 + z * 48 + t0;
    const float* Fc  = F + b * 5308416 + y * 110592 + x * 2304 + z * 48 + t0;

    float aphy = 0.f;

    #pragma unroll 1
    for (int k = 0; k < 4; ++k, ++y, Pc += 36864, Vyc += 110592, Fc += 110592) {
        const AxisP ay = axis_params(y, S); // uniform per iteration

        const float4 dPdz = az.w * (ld4(Pc + az.op1 * 16)    - ld4(Pc + az.om1 * 16));
        const float4 dPdx = ax.w * (ld4(Pc + ax.op1 * 768)   - ld4(Pc + ax.om1 * 768));
        const float4 dPdy = ay.w * (ld4(Pc + ay.op1 * 36864) - ld4(Pc + ay.om1 * 36864));

        const float* Vxc = Vyc + 16;
        const float* Vzc = Vyc + 32;
        const float4 vy = ld4(Vyc), vx = ld4(Vxc), vz = ld4(Vzc);

        float4 e4 = make_float4(0.f, 0.f, 0.f, 0.f);

        { // channel 0: Vy
            float4 dz, lz, dx_, lx, dy_, ly;
            gboth_g(Vyc, vy, az, 48, dz, lz);
            gboth_g(Vyc, vy, ax, 2304, dx_, lx);
            gboth_g(Vyc, vy, ay, 110592, dy_, ly);
            const float4 dt = d1t(vy, Vyc, t0);
            const float4 fy = ld4(Fc);
            const float4 e = dt + vx * dx_ + vy * dy_ + vz * dz + dPdy
                             + (-re) * (lz + lx + ly) + fy;
            aphy += sum2(e);
            e4 = e4 + dy_;
        }
        { // channel 1: Vx
            float4 dz, lz, dx_, lx, dy_, ly;
            gboth_g(Vxc, vx, az, 48, dz, lz);
            gboth_g(Vxc, vx, ax, 2304, dx_, lx);
            gboth_g(Vxc, vx, ay, 110592, dy_, ly);
            const float4 dt = d1t(vx, Vxc, t0);
            const float4 fx = ld4(Fc + 16);
            const float4 e = dt + vx * dx_ + vy * dy_ + vz * dz + dPdx
                             + (-re) * (lz + lx + ly) + fx;
            aphy += sum2(e);
            e4 = e4 + dx_;
        }
        { // channel 2: Vz
            float4 dz, lz, dx_, lx, dy_, ly;
            gboth_g(Vzc, vz, az, 48, dz, lz);
            gboth_g(Vzc, vz, ax, 2304, dx_, lx);
            gboth_g(Vzc, vz, ay, 110592, dy_, ly);
            const float4 dt = d1t(vz, Vzc, t0);
            const float4 fz = ld4(Fc + 32);
            const float4 e = dt + vx * dx_ + vy * dy_ + vz * dz + dPdz
                             + (-re) * (lz + lx + ly) + fz;
            aphy += sum2(e);
            e4 = e4 + dz;
        }
        aphy += sum2(e4);
    }

    #pragma unroll
    for (int off = 32; off > 0; off >>= 1) aphy += __shfl_down(aphy, off);
    __shared__ float sred[3];
    if ((tid & 63) == 0) sred[tid >> 6] = aphy;
    __syncthreads();
    if (tid == 0) atomicAdd(&ws[2], sred[0] + sred[1] + sred[2]);
}

// ---------------- elementwise streaming kernel ----------------
// 1728 blocks * 256 threads * 2 chunks = NC exactly.
__global__ __launch_bounds__(256) void elem_loss(
    const float* __restrict__ Cmat, const float* __restrict__ Xa,
    const float* __restrict__ X1a, const float* __restrict__ Xlast,
    const float* __restrict__ Y, float* __restrict__ ws)
{
    float am1 = 0.f, am2 = 0.f, at1 = 0.f, at2 = 0.f;

    #pragma unroll 1
    for (int idx = blockIdx.x * 256 + threadIdx.x; idx < NC; idx += 1728 * 256) {
        const int f = idx << 2;
        const float4 yv  = ld4(Y + f);
        const float4 x1v = ld4(X1a + f);
        const float4 xv  = ld4(Xa + f);
        const float4 cv  = ld4(Cmat + f);
        am1 += sum2(x1v - yv);
        am2 += sum2(xv - yv);
        at2 += sum2(cv - yv);
        const float yp0 = ((f & 15) == 0) ? Xlast[f >> 4] : Y[f - 1];
        at1 += sum2(make_float4(yp0, yv.x, yv.y, yv.z) - yv);
    }

    #pragma unroll
    for (int off = 32; off > 0; off >>= 1) {
        am1 += __shfl_down(am1, off);
        am2 += __shfl_down(am2, off);
        at1 += __shfl_down(at1, off);
        at2 += __shfl_down(at2, off);
    }
    __shared__ float sred[4][4];
    const int wv = threadIdx.x >> 6;
    if ((threadIdx.x & 63) == 0) {
        sred[wv][0] = am1; sred[wv][1] = am2; sred[wv][2] = at1; sred[wv][3] = at2;
    }
    __syncthreads();
    if (threadIdx.x == 0) {
        float s0 = 0.f, s1 = 0.f, s2 = 0.f, s3 = 0.f;
        #pragma unroll
        for (int w = 0; w < 4; ++w) {
            s0 += sred[w][0]; s1 += sred[w][1]; s2 += sred[w][2]; s3 += sred[w][3];
        }
        atomicAdd(&ws[0], s0);
        atomicAdd(&ws[1], s1);
        atomicAdd(&ws[3], s2);
        atomicAdd(&ws[4], s3);
    }
}

__global__ void finalize_kernel(const float* __restrict__ ws, float* __restrict__ out) {
    const float invN = 1.0f / (float)NTOT;
    const float m1  = ws[0] * invN;
    const float m2  = ws[1] * invN;
    const float phy = ws[2] * invN;
    const float t1  = ws[3] * invN;
    const float t2  = ws[4] * invN;
    out[0] = m1;
    out[1] = m2;
    out[2] = phy;
    out[3] = (t1 < t2) ? (t2 - t1) : 0.0f;
}

extern "C" void kernel_launch(void* const* d_in, const int* in_sizes, int n_in,
                              void* d_out, int out_size, void* d_ws, size_t ws_size,
                              hipStream_t stream) {
    // 0 C_all, 1 V_all, 2 P_all, 3 X_all, 4 X1_all, 5 F_all, 6 Re, 7 X_last,
    // 8 Y_data, 9 maskd0, 10 maskd1, 11 maskd2
    const float* Cmat  = (const float*)d_in[0];
    const float* V     = (const float*)d_in[1];
    const float* P     = (const float*)d_in[2];
    const float* Xa    = (const float*)d_in[3];
    const float* X1a   = (const float*)d_in[4];
    const float* F     = (const float*)d_in[5];
    const float* Rep   = (const float*)d_in[6];
    const float* Xlast = (const float*)d_in[7];
    const float* Y     = (const float*)d_in[8];

    float* ws  = (float*)d_ws;
    float* out = (float*)d_out;

    hipMemsetAsync(ws, 0, 5 * sizeof(float), stream);
    elem_loss<<<1728, 256, 0, stream>>>(Cmat, Xa, X1a, Xlast, Y, ws);
    dim3 pgrid(S, 12, 2);
    phys_loss<<<pgrid, 192, 0, stream>>>(V, P, F, Rep, ws);
    finalize_kernel<<<1, 1, 0, stream>>>(ws, out);
}